// Round 7
// baseline (427.143 us; speedup 1.0000x reference)
//
#include <hip/hip_runtime.h>
#include <math.h>

#define N_NODES 131072
#define N_DST   16384
#define DEG     16
#define HID     256
#define N_EDGES 262144

typedef __bf16 bf16_8 __attribute__((ext_vector_type(8)));
typedef float  f32_4  __attribute__((ext_vector_type(4)));

// tanh-approx gelu, |err| <~1e-3 (threshold 2.2e-2).
// log2(e) folded into polynomial constants (direct v_exp_f32); IEEE divide
// replaced by v_rcp_f32. ~7 VALU ops per gelu.
__device__ __forceinline__ float gelu_f(float v) {
    float u = fmaf(v * v, -0.10294324f, -2.30220819f) * v;
    float e;
    asm("v_exp_f32 %0, %1" : "=v"(e) : "v"(u));   // e = 2^u = exp(-t)
    return v * __builtin_amdgcn_rcpf(1.0f + e);
}
__device__ __forceinline__ f32_4 zero4() {
    f32_4 z; z[0] = 0.f; z[1] = 0.f; z[2] = 0.f; z[3] = 0.f; return z;
}

// async global->LDS, 16B per lane. LDS side must be wave-uniform base + lane*16.
__device__ __forceinline__ void load_lds16(const __bf16* g, __bf16* l) {
    __builtin_amdgcn_global_load_lds(
        (__attribute__((address_space(1))) void*)g,
        (__attribute__((address_space(3))) void*)l, 16, 0, 0);
}

// ---------------- prep (fp32->bf16 weights) + enc1, merged -----------------
// blocks [0,2304): prep (2304*256 == 589824 exactly); blocks [2304,4352): enc1.
// Independent outputs (wb vs hA) -> safe to overlap in one dispatch.
__global__ __launch_bounds__(256) void prep_enc1(
    __bf16* __restrict__ wb,
    const float* __restrict__ w2, const float* __restrict__ w3,
    const float* __restrict__ mw1, const float* __restrict__ mw2,
    const float* __restrict__ mw3,
    const float* __restrict__ x, const float* __restrict__ ew1,
    const float* __restrict__ eb1, __bf16* __restrict__ h1)
{
    if (blockIdx.x < 2304) {
        int i = blockIdx.x * 256 + threadIdx.x;
        float v;
        if      (i <  65536) v = w2[i];
        else if (i < 131072) v = w3[i - 65536];
        else if (i < 393216) v = mw1[i - 131072];
        else if (i < 524288) v = mw2[i - 393216];
        else                 v = mw3[i - 524288];
        wb[i] = (__bf16)v;
        return;
    }
    const int bid = blockIdx.x - 2304;
    const int c8   = threadIdx.x & 31;
    const int nloc = threadIdx.x >> 5;
    float w[24], bb[8];
    #pragma unroll
    for (int i = 0; i < 6; i++) *(float4*)&w[i * 4] = ((const float4*)ew1)[c8 * 6 + i];
    *(float4*)&bb[0] = ((const float4*)eb1)[c8 * 2 + 0];
    *(float4*)&bb[4] = ((const float4*)eb1)[c8 * 2 + 1];
    for (int n = bid * 8 + nloc; n < N_NODES; n += 2048 * 8) {
        float x0 = x[n * 3 + 0], x1 = x[n * 3 + 1], x2 = x[n * 3 + 2];
        bf16_8 o;
        #pragma unroll
        for (int j = 0; j < 8; j++) {
            float v = fmaf(x2, w[j * 3 + 2],
                      fmaf(x1, w[j * 3 + 1],
                      fmaf(x0, w[j * 3 + 0], bb[j])));
            o[j] = (__bf16)gelu_f(v);
        }
        *(bf16_8*)&h1[(size_t)n * 256 + c8 * 8] = o;
    }
}

// ---------------- enc23 v2: 128 rows/block, 512 thr, all-async dbuf --------
// Wave grid 2x4 -> 64x64 wave tiles both phases (af 4 + bfr 4 = 8 reads per
// K-step for 16 MFMA). A slab staged via global_load_lds (no reg round-trip),
// double-buffered with the W slab: one barrier per K-slab, drain hidden under
// MFMA. LDS = sA 2x16 + sB 2x32 + sH2 64 = 160 KB -> 1 block x 8 waves/CU.
// Same K-accumulation order as v1 -> bit-identical numerics.
__global__ __launch_bounds__(512, 1) void enc23_kernel(
    __bf16* __restrict__ hA,
    const __bf16* __restrict__ W2, const float* __restrict__ b2,
    const __bf16* __restrict__ W3, const float* __restrict__ b3,
    const float* __restrict__ pos, const float* __restrict__ bfour)
{
    __shared__ __align__(16) __bf16 sA[2][8192];     // 2x16 KB A slab [128][64]
    __shared__ __align__(16) __bf16 sB[2][16384];    // 2x32 KB W slab [256][64]
    __shared__ __align__(16) __bf16 sH2[32768];      // 64 KB h2 [128][256] A-layout

    const int tid = threadIdx.x;
    const int m0  = blockIdx.x * 128;
    const int wave = tid >> 6, lane = tid & 63, ln = lane & 15, quad = lane >> 4;
    const int wm = wave >> 2, wn = wave & 3;         // 2 x 4 wave grid

    auto stage_a = [&](int kb, int p) {
        #pragma unroll
        for (int i = 0; i < 2; i++) {
            int idx = i * 512 + tid;
            int r = idx >> 3, kg = (idx & 7) ^ (r & 7);
            load_lds16(hA + (size_t)(m0 + r) * 256 + kb * 64 + kg * 8, &sA[p][idx * 8]);
        }
    };
    auto stage_w = [&](const __bf16* W, int kb, int p) {
        #pragma unroll
        for (int i = 0; i < 4; i++) {
            int idx = i * 512 + tid;
            int r = idx >> 3, kg = (idx & 7) ^ (r & 7);
            load_lds16(W + (size_t)r * 256 + kb * 64 + kg * 8, &sB[p][idx * 8]);
        }
    };

    f32_4 acc[4][4];
    #pragma unroll
    for (int i = 0; i < 4; i++)
        #pragma unroll
        for (int j = 0; j < 4; j++) acc[i][j] = zero4();

    // prologue: slab 0 of A and W2
    stage_a(0, 0);
    stage_w(W2, 0, 0);
    __syncthreads();

    // ---- phase 1: h2 = gelu(h1 @ W2^T + b2) ----
    #pragma unroll
    for (int kb = 0; kb < 4; kb++) {
        if (kb < 3) {
            stage_a(kb + 1, (kb + 1) & 1);
            stage_w(W2, kb + 1, (kb + 1) & 1);
        }
        #pragma unroll
        for (int ks = 0; ks < 2; ks++) {
            int c = ks * 4 + quad;
            bf16_8 af[4], bfr[4];
            #pragma unroll
            for (int mt = 0; mt < 4; mt++) {
                int mr = wm * 64 + mt * 16 + ln;
                af[mt] = *(const bf16_8*)&sA[kb & 1][mr * 64 + ((c ^ (mr & 7)) * 8)];
            }
            #pragma unroll
            for (int nt = 0; nt < 4; nt++) {
                int nr = wn * 64 + nt * 16 + ln;
                bfr[nt] = *(const bf16_8*)&sB[kb & 1][nr * 64 + ((c ^ (nr & 7)) * 8)];
            }
            #pragma unroll
            for (int mt = 0; mt < 4; mt++)
                #pragma unroll
                for (int nt = 0; nt < 4; nt++)
                    acc[mt][nt] = __builtin_amdgcn_mfma_f32_16x16x32_bf16(af[mt], bfr[nt], acc[mt][nt], 0, 0, 0);
        }
        if (kb == 3) break;
        __syncthreads();
    }
    // stage W3(0) -> sB[0] during epi1 (sB[0] last read at kb=2, done)
    stage_w(W3, 0, 0);
    // epi1 -> sH2 (add-rotation swizzle)
    #pragma unroll
    for (int nt = 0; nt < 4; nt++) {
        int col = wn * 64 + nt * 16 + ln;
        float bb = b2[col];
        #pragma unroll
        for (int mt = 0; mt < 4; mt++) {
            #pragma unroll
            for (int r = 0; r < 4; r++) {
                int row = wm * 64 + mt * 16 + quad * 4 + r;
                sH2[row * 256 + ((col + row * 8) & 255)] = (__bf16)gelu_f(acc[mt][nt][r] + bb);
            }
        }
    }
    #pragma unroll
    for (int i = 0; i < 4; i++)
        #pragma unroll
        for (int j = 0; j < 4; j++) acc[i][j] = zero4();
    __syncthreads();   // sH2 visible; W3(0) landed; all phase-1 slab reads done

    // ---- phase 2: h = h2 @ W3^T + b3 + fourier ----
    #pragma unroll
    for (int kb = 0; kb < 4; kb++) {
        if (kb < 3) stage_w(W3, kb + 1, (kb + 1) & 1);
        #pragma unroll
        for (int ks = 0; ks < 2; ks++) {
            int c = ks * 4 + quad;
            int k0 = kb * 64 + ks * 32 + quad * 8;
            bf16_8 af[4], bfr[4];
            #pragma unroll
            for (int mt = 0; mt < 4; mt++) {
                int mr = wm * 64 + mt * 16 + ln;
                af[mt] = *(const bf16_8*)&sH2[mr * 256 + ((k0 + mr * 8) & 255)];
            }
            #pragma unroll
            for (int nt = 0; nt < 4; nt++) {
                int nr = wn * 64 + nt * 16 + ln;
                bfr[nt] = *(const bf16_8*)&sB[kb & 1][nr * 64 + ((c ^ (nr & 7)) * 8)];
            }
            #pragma unroll
            for (int mt = 0; mt < 4; mt++)
                #pragma unroll
                for (int nt = 0; nt < 4; nt++)
                    acc[mt][nt] = __builtin_amdgcn_mfma_f32_16x16x32_bf16(af[mt], bfr[nt], acc[mt][nt], 0, 0, 0);
        }
        __syncthreads();
    }
    // epi2: + b3 + fourier -> per-wave transpose (reuse sB) -> 16B stores
    __bf16* buf = ((__bf16*)sB) + wave * 4096;
    float b3r[4], Bc0[4], Bc1[4];
    #pragma unroll
    for (int nt = 0; nt < 4; nt++) {
        int col = wn * 64 + nt * 16 + ln;
        b3r[nt] = b3[col];
        int jm = col & 127;
        Bc0[nt] = bfour[jm * 2 + 0];
        Bc1[nt] = bfour[jm * 2 + 1];
    }
    const bool iscos = (wn < 2);
    #pragma unroll
    for (int mt = 0; mt < 4; mt++) {
        #pragma unroll
        for (int r = 0; r < 4; r++) {
            int rowL = mt * 16 + quad * 4 + r;
            int rowE = m0 + wm * 64 + rowL;
            float p0 = pos[rowE * 2 + 0], p1 = pos[rowE * 2 + 1];
            #pragma unroll
            for (int nt = 0; nt < 4; nt++) {
                float f = 6.2831853071795864f * fmaf(p1, Bc1[nt], p0 * Bc0[nt]);
                float v = acc[mt][nt][r] + b3r[nt] + (iscos ? __cosf(f) : __sinf(f));
                int colL = nt * 16 + ln;
                buf[rowL * 64 + ((colL + rowL * 8) & 63)] = (__bf16)v;
            }
        }
    }
    // wave-private buf: same-wave RAW ordered by lgkmcnt (proven pattern)
    #pragma unroll
    for (int p = 0; p < 8; p++) {
        int rowL = p * 8 + (lane >> 3);
        int c8 = lane & 7;
        bf16_8 vv = *(const bf16_8*)&buf[rowL * 64 + ((c8 * 8 + rowL * 8) & 63)];
        *(bf16_8*)&hA[(size_t)(m0 + wm * 64 + rowL) * 256 + wn * 64 + c8 * 8] = vv;
    }
}

// ---------------- msg_fused v7 ---------------------------------------------
// v6b structure, wave grid re-shaped 2x4: phase-1 tile 64x32 (acc1 4x2),
// phase-2 tile 64x64 (acc2 4x4) -> phase-2 reads 8/K-step instead of 10
// (-15% total ds_read_b128) and half the phase-2 B-frag registers.
// Identical staging/barrier structure and K-order -> bit-identical numerics.
__global__ __launch_bounds__(512, 1) void msg_fused(
    const __bf16* __restrict__ h, const int* __restrict__ edges,
    const __bf16* __restrict__ W1a, const __bf16* __restrict__ dmat,
    const __bf16* __restrict__ W2, const float* __restrict__ b2,
    __bf16* __restrict__ p2)
{
    __shared__ __align__(16) __bf16 sH[32768];       // 64 KB gathered h_src [128][256]
    __shared__ __align__(16) __bf16 sB[2][16384];    // 64 KB double-buffered W slab
    __shared__ __align__(16) __bf16 sM1[16384];      // 32 KB m1 quarter (A-layout)

    const int tid = threadIdx.x;
    const int e0  = blockIdx.x * 128;
    const int wave = tid >> 6, lane = tid & 63, ln = lane & 15, quad = lane >> 4;
    const int wm = wave >> 2, wn = wave & 3;   // 2 x 4 wave grid

    int* s_src = (int*)sM1;   // overlay: consumed in gather prologue only
    if (tid < 128) s_src[tid] = edges[2 * (e0 + tid) + 1];
    __syncthreads();

    auto stage_w1 = [&](int q, int kb, int p) {
        const __bf16* s0 = W1a + (size_t)(q * 128) * 512 + kb * 128;
        #pragma unroll
        for (int i = 0; i < 4; i++) {
            int idx = i * 512 + tid;
            int r = idx >> 4, kg = (idx & 15) ^ (r & 7);
            load_lds16(s0 + r * 512 + kg * 8, &sB[p][idx * 8]);
        }
    };
    auto stage_w2 = [&](int q, int kb2, int p) {
        const __bf16* s0 = W2 + q * 128 + kb2 * 64;
        #pragma unroll
        for (int i = 0; i < 4; i++) {
            int idx = i * 512 + tid;
            int r = idx >> 3, kg = (idx & 7) ^ (r & 7);
            load_lds16(s0 + (size_t)r * 512 + kg * 8, &sB[p][idx * 8]);
        }
    };

    // gather h[src] -> sH (XOR-chunk layout) + first W1a slab; one drain.
    #pragma unroll
    for (int i = 0; i < 8; i++) {
        int idx = i * 512 + tid;
        int row = idx >> 5, kg = (idx & 31) ^ (row & 7);
        load_lds16(h + (size_t)s_src[row] * 256 + kg * 8, &sH[idx * 8]);
    }
    stage_w1(0, 0, 0);
    __syncthreads();

    f32_4 acc2[4][4];
    #pragma unroll
    for (int i = 0; i < 4; i++)
        #pragma unroll
        for (int j = 0; j < 4; j++) acc2[i][j] = zero4();

    #pragma unroll 1
    for (int q = 0; q < 4; q++) {
        // per-quarter bias+d registers (b1 pre-folded into dmat)
        const int colbase = q * 128 + wn * 32;
        float bd[4][2];
        #pragma unroll
        for (int nt = 0; nt < 2; nt++) {
            #pragma unroll
            for (int mt = 0; mt < 4; mt++) {
                int gid = blockIdx.x * 8 + wm * 4 + mt;
                bd[mt][nt] = (float)dmat[(size_t)gid * 512 + colbase + nt * 16 + ln];
            }
        }
        f32_4 acc1[4][2];
        #pragma unroll
        for (int i = 0; i < 4; i++)
            #pragma unroll
            for (int j = 0; j < 2; j++) acc1[i][j] = zero4();

        // ---- iter A: compute W1a(q,0) in sB[0]; stage W1a(q,1) -> sB[1] ----
        stage_w1(q, 1, 1);
        #pragma unroll
        for (int ks = 0; ks < 4; ks++) {
            int c = ks * 4 + quad;          // slab chunk 0..15 == sH chunk (kb=0)
            bf16_8 af[4], bfr[2];
            #pragma unroll
            for (int mt = 0; mt < 4; mt++) {
                int mr = wm * 64 + mt * 16 + ln;
                af[mt] = *(const bf16_8*)&sH[mr * 256 + ((c ^ (mr & 7)) * 8)];
            }
            #pragma unroll
            for (int nt = 0; nt < 2; nt++) {
                int nr = wn * 32 + nt * 16 + ln;
                bfr[nt] = *(const bf16_8*)&sB[0][nr * 128 + ((c ^ (nr & 7)) * 8)];
            }
            #pragma unroll
            for (int mt = 0; mt < 4; mt++)
                #pragma unroll
                for (int nt = 0; nt < 2; nt++)
                    acc1[mt][nt] = __builtin_amdgcn_mfma_f32_16x16x32_bf16(af[mt], bfr[nt], acc1[mt][nt], 0, 0, 0);
        }
        __syncthreads();

        // ---- iter B: compute W1a(q,1) in sB[1]; stage W2(q,0) -> sB[0] ----
        stage_w2(q, 0, 0);
        #pragma unroll
        for (int ks = 0; ks < 4; ks++) {
            int cb = ks * 4 + quad;         // slab chunk 0..15
            int ca = 16 + cb;               // sH chunk (kb=1 half)
            bf16_8 af[4], bfr[2];
            #pragma unroll
            for (int mt = 0; mt < 4; mt++) {
                int mr = wm * 64 + mt * 16 + ln;
                af[mt] = *(const bf16_8*)&sH[mr * 256 + ((ca ^ (mr & 7)) * 8)];
            }
            #pragma unroll
            for (int nt = 0; nt < 2; nt++) {
                int nr = wn * 32 + nt * 16 + ln;
                bfr[nt] = *(const bf16_8*)&sB[1][nr * 128 + ((cb ^ (nr & 7)) * 8)];
            }
            #pragma unroll
            for (int mt = 0; mt < 4; mt++)
                #pragma unroll
                for (int nt = 0; nt < 2; nt++)
                    acc1[mt][nt] = __builtin_amdgcn_mfma_f32_16x16x32_bf16(af[mt], bfr[nt], acc1[mt][nt], 0, 0, 0);
        }
        // epi1: gelu(acc1 + bd) -> sM1 (A-layout, add-rotation swizzle)
        #pragma unroll
        for (int mt = 0; mt < 4; mt++) {
            #pragma unroll
            for (int nt = 0; nt < 2; nt++) {
                #pragma unroll
                for (int r = 0; r < 4; r++) {
                    int row = wm * 64 + mt * 16 + quad * 4 + r;
                    int colq = wn * 32 + nt * 16 + ln;
                    float v = gelu_f(acc1[mt][nt][r] + bd[mt][nt]);
                    sM1[row * 128 + ((colq + row * 8) & 127)] = (__bf16)v;
                }
            }
        }
        __syncthreads();   // publish sM1; sB[1] reads done; W2(q,0) landed

        // ---- iter C: compute W2(q,0) in sB[0]; stage W2(q,1) -> sB[1] ----
        stage_w2(q, 1, 1);
        #pragma unroll
        for (int ks = 0; ks < 2; ks++) {
            int k0 = ks * 32 + quad * 8;
            int cb2 = ks * 4 + quad;        // slab chunk 0..7
            bf16_8 af[4], bfr[4];
            #pragma unroll
            for (int mt = 0; mt < 4; mt++) {
                int mr = wm * 64 + mt * 16 + ln;
                af[mt] = *(const bf16_8*)&sM1[mr * 128 + ((k0 + mr * 8) & 127)];
            }
            #pragma unroll
            for (int nt = 0; nt < 4; nt++) {
                int nr = wn * 64 + nt * 16 + ln;
                bfr[nt] = *(const bf16_8*)&sB[0][nr * 64 + ((cb2 ^ (nr & 7)) * 8)];
            }
            #pragma unroll
            for (int mt = 0; mt < 4; mt++)
                #pragma unroll
                for (int nt = 0; nt < 4; nt++)
                    acc2[mt][nt] = __builtin_amdgcn_mfma_f32_16x16x32_bf16(af[mt], bfr[nt], acc2[mt][nt], 0, 0, 0);
        }
        __syncthreads();

        // ---- iter D: compute W2(q,1) in sB[1]; stage W1a(q+1,0) -> sB[0] ----
        if (q < 3) stage_w1(q + 1, 0, 0);
        #pragma unroll
        for (int ks = 0; ks < 2; ks++) {
            int k0 = 64 + ks * 32 + quad * 8;
            int cb2 = ks * 4 + quad;
            bf16_8 af[4], bfr[4];
            #pragma unroll
            for (int mt = 0; mt < 4; mt++) {
                int mr = wm * 64 + mt * 16 + ln;
                af[mt] = *(const bf16_8*)&sM1[mr * 128 + ((k0 + mr * 8) & 127)];
            }
            #pragma unroll
            for (int nt = 0; nt < 4; nt++) {
                int nr = wn * 64 + nt * 16 + ln;
                bfr[nt] = *(const bf16_8*)&sB[1][nr * 64 + ((cb2 ^ (nr & 7)) * 8)];
            }
            #pragma unroll
            for (int mt = 0; mt < 4; mt++)
                #pragma unroll
                for (int nt = 0; nt < 4; nt++)
                    acc2[mt][nt] = __builtin_amdgcn_mfma_f32_16x16x32_bf16(af[mt], bfr[nt], acc2[mt][nt], 0, 0, 0);
        }
        __syncthreads();
    }

    // pool epilogue: mean of gelu(acc2 + b2) over each 16-row group
    #pragma unroll
    for (int nt = 0; nt < 4; nt++) {
        int col = wn * 64 + nt * 16 + ln;
        float bb = b2[col];
        #pragma unroll
        for (int mt = 0; mt < 4; mt++) {
            float s = gelu_f(acc2[mt][nt][0] + bb) + gelu_f(acc2[mt][nt][1] + bb)
                    + gelu_f(acc2[mt][nt][2] + bb) + gelu_f(acc2[mt][nt][3] + bb);
            s += __shfl_xor(s, 16);
            s += __shfl_xor(s, 32);
            if (quad == 0) {
                int dstn = edges[2 * (e0 + (wm * 4 + mt) * 16)];
                p2[(size_t)dstn * HID + col] = (__bf16)(s * 0.0625f);
            }
        }
    }
}

// ---------------- mgemm (thin 128x128): used for g1d / g3 ----------------
template<int K, int GMODE, int WLD, int WOFF, bool BIAS, bool POOL_, bool F32OUT>
__global__ __launch_bounds__(256, 3) void mgemm(
    const __bf16* __restrict__ Ag, const __bf16* __restrict__ h,
    const int* __restrict__ edges, const __bf16* __restrict__ W,
    const float* __restrict__ bias, __bf16* __restrict__ Cb,
    float* __restrict__ Cf, int NB, int Nfull, int e0)
{
    __shared__ __align__(16) __bf16 sA[128 * 64];
    __shared__ __align__(16) __bf16 sB[128 * 64];
    __shared__ int s_idx[128];

    const int tid  = threadIdx.x;
    const int mblk = blockIdx.x / NB;
    const int nblk = blockIdx.x % NB;
    const int m0 = mblk * 128, n0 = nblk * 128;
    const int wave = tid >> 6, lane = tid & 63, ln = lane & 15, quad = lane >> 4;
    const int wm = wave >> 1, wn = wave & 1;

    if (GMODE) {
        if (tid < 128) {
            int r = m0 + tid;
            s_idx[tid] = (GMODE == 1) ? edges[2 * (e0 + r) + 1]
                                      : edges[2 * (DEG * r)];
        }
        __syncthreads();
    }

    const __bf16* pA[4];
    const __bf16* pB[4];
    #pragma unroll
    for (int i = 0; i < 4; i++) {
        int idx = i * 256 + tid;
        int row = idx >> 3, kg = (idx & 7) ^ (row & 7);
        pA[i] = GMODE ? h + (size_t)s_idx[row] * HID + kg * 8
                      : Ag + (size_t)(m0 + row) * K + kg * 8;
        pB[i] = W + (size_t)(n0 + row) * WLD + WOFF + kg * 8;
    }
    const int ach = quad ^ (ln & 7);
    const int aof[2] = { (wm * 64 + ln) * 64 + ach * 8, (wm * 64 + ln) * 64 + (ach ^ 4) * 8 };
    const int bof[2] = { (wn * 64 + ln) * 64 + ach * 8, (wn * 64 + ln) * 64 + (ach ^ 4) * 8 };

    f32_4 acc[4][4];
    #pragma unroll
    for (int i = 0; i < 4; i++)
        #pragma unroll
        for (int j = 0; j < 4; j++) acc[i][j] = zero4();

    bf16_8 ar[4], br[4];
    #pragma unroll
    for (int i = 0; i < 4; i++) {
        ar[i] = *(const bf16_8*)pA[i];
        br[i] = *(const bf16_8*)pB[i];
    }

    #pragma unroll
    for (int kb = 0; kb < K / 64; kb++) {
        if (kb > 0) __syncthreads();
        #pragma unroll
        for (int i = 0; i < 4; i++) {
            int idx = i * 256 + tid;
            *(bf16_8*)&sA[idx * 8] = ar[i];
            *(bf16_8*)&sB[idx * 8] = br[i];
        }
        __syncthreads();
        if (kb + 1 < K / 64) {
            #pragma unroll
            for (int i = 0; i < 4; i++) {
                ar[i] = *(const bf16_8*)(pA[i] + (kb + 1) * 64);
                br[i] = *(const bf16_8*)(pB[i] + (kb + 1) * 64);
            }
        }
        #pragma unroll
        for (int ks = 0; ks < 2; ks++) {
            bf16_8 af[4], bfr[4];
            #pragma unroll
            for (int mt = 0; mt < 4; mt++) af[mt]  = *(const bf16_8*)&sA[aof[ks] + mt * 1024];
            #pragma unroll
            for (int nt = 0; nt < 4; nt++) bfr[nt] = *(const bf16_8*)&sB[bof[ks] + nt * 1024];
            #pragma unroll
            for (int mt = 0; mt < 4; mt++)
                #pragma unroll
                for (int nt = 0; nt < 4; nt++)
                    acc[mt][nt] = __builtin_amdgcn_mfma_f32_16x16x32_bf16(af[mt], bfr[nt], acc[mt][nt], 0, 0, 0);
        }
    }

    if (POOL_) {
        #pragma unroll
        for (int nt = 0; nt < 4; nt++) {
            int col = n0 + wn * 64 + nt * 16 + ln;
            float bb = BIAS ? bias[col] : 0.f;
            #pragma unroll
            for (int mt = 0; mt < 4; mt++) {
                float s = gelu_f(acc[mt][nt][0] + bb) + gelu_f(acc[mt][nt][1] + bb)
                        + gelu_f(acc[mt][nt][2] + bb) + gelu_f(acc[mt][nt][3] + bb);
                s += __shfl_xor(s, 16);
                s += __shfl_xor(s, 32);
                if (quad == 0) {
                    int eg  = e0 + m0 + wm * 64 + mt * 16;
                    int dstn = edges[2 * eg];
                    Cb[(size_t)dstn * HID + col] = (__bf16)(s * 0.0625f);
                }
            }
        }
    } else if (F32OUT) {
        #pragma unroll
        for (int nt = 0; nt < 4; nt++) {
            int col = n0 + wn * 64 + nt * 16 + ln;
            float bb = BIAS ? bias[col] : 0.f;
            #pragma unroll
            for (int mt = 0; mt < 4; mt++) {
                #pragma unroll
                for (int r = 0; r < 4; r++) {
                    int rowE = m0 + wm * 64 + mt * 16 + quad * 4 + r;
                    Cf[(size_t)rowE * Nfull + col] = acc[mt][nt][r] + bb;
                }
            }
        }
    } else {
        // raw bf16 transpose-store (+optional bias fold, used to bake b1 into d)
        __syncthreads();
        __bf16* sw = ((wave & 2) ? sB : sA) + (wave & 1) * 4096;
        #pragma unroll
        for (int nt = 0; nt < 4; nt++) {
            float bb = BIAS ? bias[n0 + wn * 64 + nt * 16 + ln] : 0.f;
            #pragma unroll
            for (int mt = 0; mt < 4; mt++) {
                #pragma unroll
                for (int r = 0; r < 4; r++) {
                    int rowL = mt * 16 + quad * 4 + r;
                    int colL = nt * 16 + ln;
                    sw[rowL * 64 + ((colL + rowL * 8) & 63)] = (__bf16)(acc[mt][nt][r] + bb);
                }
            }
        }
        __syncthreads();
        #pragma unroll
        for (int p = 0; p < 8; p++) {
            int rowL = p * 8 + (lane >> 3);
            int c8 = lane & 7;
            bf16_8 vv = *(const bf16_8*)&sw[rowL * 64 + ((c8 * 8 + rowL * 8) & 63)];
            int rowE = m0 + wm * 64 + rowL;
            *(bf16_8*)&Cb[(size_t)rowE * Nfull + n0 + wn * 64 + c8 * 8] = vv;
        }
    }
}

extern "C" void kernel_launch(void* const* d_in, const int* in_sizes, int n_in,
                              void* d_out, int out_size, void* d_ws, size_t ws_size,
                              hipStream_t stream) {
    const float* x     = (const float*)d_in[0];
    const float* pos   = (const float*)d_in[1];
    const int*   edges = (const int*)d_in[2];
    const float* ip_w1 = (const float*)d_in[4];
    const float* ip_b1 = (const float*)d_in[5];
    const float* ip_w2 = (const float*)d_in[6];
    const float* ip_b2 = (const float*)d_in[7];
    const float* ip_w3 = (const float*)d_in[8];
    const float* ip_b3 = (const float*)d_in[9];
    const float* bfour = (const float*)d_in[10];
    const float* mw1   = (const float*)d_in[11];
    const float* mb1   = (const float*)d_in[12];
    const float* mw2   = (const float*)d_in[13];
    const float* mb2   = (const float*)d_in[14];
    const float* mw3   = (const float*)d_in[15];
    const float* mb3   = (const float*)d_in[16];

    // workspace: hA 64 MB | weights 1.125 MB | dbuf 16 MB | p2 8 MB  (~89 MB)
    char* ws = (char*)d_ws;
    __bf16* hA = (__bf16*)ws;
    size_t off = (size_t)N_NODES * HID * 2;
    __bf16* wb = (__bf16*)(ws + off);
    off += (size_t)589824 * 2;
    off = (off + 255) & ~(size_t)255;
    __bf16* dbuf = (__bf16*)(ws + off);                      // d = h_dst@W1b^T + b1
    off += (size_t)N_DST * 512 * 2;
    __bf16* p2 = (__bf16*)(ws + off);                        // pooled m2
    off += (size_t)N_DST * HID * 2;

    __bf16* w2b  = wb;
    __bf16* w3b  = wb + 65536;
    __bf16* mw1b = wb + 131072;
    __bf16* mw2b = wb + 393216;
    __bf16* mw3b = wb + 524288;

    // prep (blocks 0..2303) + enc1 (blocks 2304..4351), merged
    prep_enc1<<<4352, 256, 0, stream>>>(wb, ip_w2, ip_w3, mw1, mw2, mw3,
                                        x, ip_w1, ip_b1, hA);

    enc23_kernel<<<1024, 512, 0, stream>>>(hA, w2b, ip_b2, w3b, ip_b3, pos, bfour);

    // d[g] = h[dst(g)] @ W1b^T + b1  (16384 x 512, K=256)
    mgemm<256, 2, 512, 256, true, false, false><<<512, 256, 0, stream>>>(
        nullptr, hA, edges, mw1b, mb1, dbuf, nullptr, 4, 512, 0);

    // fused message MLP + pool: p2[dst] = mean(gelu(gelu(h_src@W1a^T+d)@W2^T+b2))
    msg_fused<<<2048, 512, 0, stream>>>(hA, edges, mw1b, dbuf, mw2b, mb2, p2);

    // out = p2 @ W3^T + b3  (16384 x 256, K=256), fp32
    mgemm<256, 0, 256, 0, true, false, true><<<256, 256, 0, stream>>>(
        p2, nullptr, nullptr, mw3b, mb3, nullptr, (float*)d_out, 2, 256, 0);
}

// Round 8
// 404.322 us; speedup vs baseline: 1.0564x; 1.0564x over previous
//
#include <hip/hip_runtime.h>
#include <math.h>

#define N_NODES 131072
#define N_DST   16384
#define DEG     16
#define HID     256
#define N_EDGES 262144

typedef __bf16 bf16_8 __attribute__((ext_vector_type(8)));
typedef float  f32_4  __attribute__((ext_vector_type(4)));

// tanh-approx gelu, |err| <~1e-3 (threshold 2.2e-2).
// log2(e) folded into polynomial constants (direct v_exp_f32); IEEE divide
// replaced by v_rcp_f32. ~7 VALU ops per gelu.
__device__ __forceinline__ float gelu_f(float v) {
    float u = fmaf(v * v, -0.10294324f, -2.30220819f) * v;
    float e;
    asm("v_exp_f32 %0, %1" : "=v"(e) : "v"(u));   // e = 2^u = exp(-t)
    return v * __builtin_amdgcn_rcpf(1.0f + e);
}
__device__ __forceinline__ f32_4 zero4() {
    f32_4 z; z[0] = 0.f; z[1] = 0.f; z[2] = 0.f; z[3] = 0.f; return z;
}

// async global->LDS, 16B per lane. LDS side must be wave-uniform base + lane*16.
__device__ __forceinline__ void load_lds16(const __bf16* g, __bf16* l) {
    __builtin_amdgcn_global_load_lds(
        (__attribute__((address_space(1))) void*)g,
        (__attribute__((address_space(3))) void*)l, 16, 0, 0);
}

// ---------------- prep: fp32 -> bf16 weights ----------------
__global__ void prep_kernel(__bf16* __restrict__ out,
                            const float* __restrict__ w2,
                            const float* __restrict__ w3,
                            const float* __restrict__ mw1,
                            const float* __restrict__ mw2,
                            const float* __restrict__ mw3) {
    int i = blockIdx.x * 256 + threadIdx.x;
    if (i >= 589824) return;
    float v;
    if      (i <  65536) v = w2[i];
    else if (i < 131072) v = w3[i - 65536];
    else if (i < 393216) v = mw1[i - 131072];
    else if (i < 524288) v = mw2[i - 393216];
    else                 v = mw3[i - 524288];
    out[i] = (__bf16)v;
}

// ---------------- enc123: fused encoder L1+L2+L3 -> hA ----------------------
// 64 rows/block, 256 thr (R6's proven enc23 v1 structure). enc1 is inlined:
// h1 = gelu(x @ W1^T + b1) computed in-register in the prologue (exact enc1
// formula/order -> bit-identical) and written straight to the sH slab in
// XOR-chunk layout -- no h1 HBM round-trip (saves 128 MB traffic + a launch),
// no per-kb sA staging. sH holds h1 (XOR-chunk) for phase 1, then is
// overwritten by h2 (add-rotation) in epi1: lifetimes disjoint, waves only
// touch their own 32-row band. LDS = 32 (sH) + 32 (sB) = 64 KB -> 2 blocks/CU.
__global__ __launch_bounds__(256, 2) void enc123_kernel(
    const float* __restrict__ x, const float* __restrict__ ew1,
    const float* __restrict__ eb1, __bf16* __restrict__ hA,
    const __bf16* __restrict__ W2, const float* __restrict__ b2,
    const __bf16* __restrict__ W3, const float* __restrict__ b3,
    const float* __restrict__ pos, const float* __restrict__ bfour)
{
    __shared__ __align__(16) __bf16 sH[64 * 256];   // 32 KB h1 -> h2
    __shared__ __align__(16) __bf16 sB[16384];      // 32 KB W slab / epi transpose

    const int tid = threadIdx.x;
    const int m0  = blockIdx.x * 64;
    const int wave = tid >> 6, lane = tid & 63, ln = lane & 15, quad = lane >> 4;
    const int wm = wave >> 1, wn = wave & 1;

    auto stage_w = [&](const __bf16* W, int kb) {
        #pragma unroll
        for (int i = 0; i < 8; i++) {
            int idx = i * 256 + tid;
            int row = idx >> 3, kg = (idx & 7) ^ (row & 7);
            load_lds16(W + (size_t)row * 256 + kb * 64 + kg * 8, &sB[idx * 8]);
        }
    };

    // prologue: issue W2(0) DMA, then compute h1 under it (exact enc1 math).
    stage_w(W2, 0);
    {
        const int c8 = tid & 31;     // col-chunk 0..31 (8 cols)
        const int rl = tid >> 5;     // row phase 0..7
        float w[24], bb[8];
        #pragma unroll
        for (int i = 0; i < 6; i++) *(float4*)&w[i * 4] = ((const float4*)ew1)[c8 * 6 + i];
        *(float4*)&bb[0] = ((const float4*)eb1)[c8 * 2 + 0];
        *(float4*)&bb[4] = ((const float4*)eb1)[c8 * 2 + 1];
        #pragma unroll
        for (int rr = 0; rr < 8; rr++) {
            int row = rr * 8 + rl;
            int g = m0 + row;
            float x0 = x[g * 3 + 0], x1 = x[g * 3 + 1], x2 = x[g * 3 + 2];
            bf16_8 o;
            #pragma unroll
            for (int j = 0; j < 8; j++) {
                float v = fmaf(x2, w[j * 3 + 2],
                          fmaf(x1, w[j * 3 + 1],
                          fmaf(x0, w[j * 3 + 0], bb[j])));
                o[j] = (__bf16)gelu_f(v);
            }
            *(bf16_8*)&sH[row * 256 + ((c8 ^ (row & 7)) * 8)] = o;
        }
    }
    __syncthreads();   // sH h1 visible + W2(0) landed

    f32_4 acc[2][8];
    #pragma unroll
    for (int i = 0; i < 2; i++)
        #pragma unroll
        for (int j = 0; j < 8; j++) acc[i][j] = zero4();

    // ---- phase 1: h2 = gelu(h1 @ W2^T + b2) ----
    #pragma unroll
    for (int kb = 0; kb < 4; kb++) {
        #pragma unroll
        for (int ks = 0; ks < 2; ks++) {
            int c = ks * 4 + quad;
            bf16_8 af[2], bfr[8];
            #pragma unroll
            for (int mt = 0; mt < 2; mt++) {
                int mr = wm * 32 + mt * 16 + ln;
                af[mt] = *(const bf16_8*)&sH[mr * 256 + ((kb * 8 + (c ^ (mr & 7))) * 8)];
            }
            #pragma unroll
            for (int nt = 0; nt < 8; nt++) {
                int nr = wn * 128 + nt * 16 + ln;
                bfr[nt] = *(const bf16_8*)&sB[nr * 64 + ((c ^ (nr & 7)) * 8)];
            }
            #pragma unroll
            for (int mt = 0; mt < 2; mt++)
                #pragma unroll
                for (int nt = 0; nt < 8; nt++)
                    acc[mt][nt] = __builtin_amdgcn_mfma_f32_16x16x32_bf16(af[mt], bfr[nt], acc[mt][nt], 0, 0, 0);
        }
        __syncthreads();   // sB reads done
        if (kb < 3) {
            stage_w(W2, kb + 1);
            __syncthreads();
        }
    }
    // stage W3(0) during epi1 (sB free after last sync)
    stage_w(W3, 0);
    // epi1 -> sH (add-rotation swizzle); own-row band only
    #pragma unroll
    for (int nt = 0; nt < 8; nt++) {
        int col = wn * 128 + nt * 16 + ln;
        float bb = b2[col];
        #pragma unroll
        for (int mt = 0; mt < 2; mt++) {
            #pragma unroll
            for (int r = 0; r < 4; r++) {
                int row = wm * 32 + mt * 16 + quad * 4 + r;
                sH[row * 256 + ((col + row * 8) & 255)] = (__bf16)gelu_f(acc[mt][nt][r] + bb);
            }
        }
    }
    #pragma unroll
    for (int i = 0; i < 2; i++)
        #pragma unroll
        for (int j = 0; j < 8; j++) acc[i][j] = zero4();
    __syncthreads();   // h2 visible + W3(0) landed

    // ---- phase 2: h = h2 @ W3^T + b3 + fourier ----
    #pragma unroll
    for (int kb = 0; kb < 4; kb++) {
        #pragma unroll
        for (int ks = 0; ks < 2; ks++) {
            int c = ks * 4 + quad;
            int k0 = kb * 64 + ks * 32 + quad * 8;
            bf16_8 af[2], bfr[8];
            #pragma unroll
            for (int mt = 0; mt < 2; mt++) {
                int mr = wm * 32 + mt * 16 + ln;
                af[mt] = *(const bf16_8*)&sH[mr * 256 + ((k0 + mr * 8) & 255)];
            }
            #pragma unroll
            for (int nt = 0; nt < 8; nt++) {
                int nr = wn * 128 + nt * 16 + ln;
                bfr[nt] = *(const bf16_8*)&sB[nr * 64 + ((c ^ (nr & 7)) * 8)];
            }
            #pragma unroll
            for (int mt = 0; mt < 2; mt++)
                #pragma unroll
                for (int nt = 0; nt < 8; nt++)
                    acc[mt][nt] = __builtin_amdgcn_mfma_f32_16x16x32_bf16(af[mt], bfr[nt], acc[mt][nt], 0, 0, 0);
        }
        __syncthreads();   // sB reads done
        if (kb < 3) {
            stage_w(W3, kb + 1);
            __syncthreads();
        }
    }
    // epi2: + b3 + fourier -> per-wave transpose (reuse sB) -> 16B stores
    __bf16* buf = sB + wave * 4096;
    float b3r[8], Bc0[8], Bc1[8];
    #pragma unroll
    for (int nt = 0; nt < 8; nt++) {
        int col = wn * 128 + nt * 16 + ln;
        b3r[nt] = b3[col];
        int jm = col & 127;
        Bc0[nt] = bfour[jm * 2 + 0];
        Bc1[nt] = bfour[jm * 2 + 1];
    }
    const bool iscos = (wn == 0);
    #pragma unroll
    for (int mt = 0; mt < 2; mt++) {
        #pragma unroll
        for (int r = 0; r < 4; r++) {
            int rowL = mt * 16 + quad * 4 + r;
            int rowE = m0 + wm * 32 + rowL;
            float p0 = pos[rowE * 2 + 0], p1 = pos[rowE * 2 + 1];
            #pragma unroll
            for (int nt = 0; nt < 8; nt++) {
                float f = 6.2831853071795864f * fmaf(p1, Bc1[nt], p0 * Bc0[nt]);
                float v = acc[mt][nt][r] + b3r[nt] + (iscos ? __cosf(f) : __sinf(f));
                int colL = nt * 16 + ln;
                buf[rowL * 128 + ((colL + rowL * 8) & 127)] = (__bf16)v;
            }
        }
    }
    // wave-private buf: same-wave RAW ordered by lgkmcnt (proven pattern)
    #pragma unroll
    for (int p = 0; p < 8; p++) {
        int rowL = p * 4 + (lane >> 4);
        int c8 = lane & 15;
        bf16_8 vv = *(const bf16_8*)&buf[rowL * 128 + ((c8 * 8 + rowL * 8) & 127)];
        *(bf16_8*)&hA[(size_t)(m0 + wm * 32 + rowL) * 256 + wn * 128 + c8 * 8] = vv;
    }
}

// ---------------- msg_fused v6b (R6 verbatim) + setprio A/B ----------------
// 128 edges/block, 512 threads (8 waves, 4x2 grid). h_src gathered once into
// sH; weight slabs double-buffered (stage(next) -> compute(cur) -> sync).
// LDS = 160 KB exactly; s_src overlays sM1. setprio(1) wraps each MFMA nest
// (T5 A/B -- isolated by this kernel's own dispatch time).
__global__ __launch_bounds__(512, 1) void msg_fused(
    const __bf16* __restrict__ h, const int* __restrict__ edges,
    const __bf16* __restrict__ W1a, const __bf16* __restrict__ dmat,
    const __bf16* __restrict__ W2, const float* __restrict__ b2,
    __bf16* __restrict__ p2)
{
    __shared__ __align__(16) __bf16 sH[32768];       // 64 KB gathered h_src [128][256]
    __shared__ __align__(16) __bf16 sB[2][16384];    // 64 KB double-buffered W slab
    __shared__ __align__(16) __bf16 sM1[16384];      // 32 KB m1 quarter (A-layout)

    const int tid = threadIdx.x;
    const int e0  = blockIdx.x * 128;
    const int wave = tid >> 6, lane = tid & 63, ln = lane & 15, quad = lane >> 4;
    const int wm = wave >> 1, wn = wave & 1;   // 4 x 2 wave grid

    int* s_src = (int*)sM1;   // overlay: consumed in gather prologue only
    if (tid < 128) s_src[tid] = edges[2 * (e0 + tid) + 1];
    __syncthreads();

    auto stage_w1 = [&](int q, int kb, int p) {
        const __bf16* s0 = W1a + (size_t)(q * 128) * 512 + kb * 128;
        #pragma unroll
        for (int i = 0; i < 4; i++) {
            int idx = i * 512 + tid;
            int r = idx >> 4, kg = (idx & 15) ^ (r & 7);
            load_lds16(s0 + r * 512 + kg * 8, &sB[p][idx * 8]);
        }
    };
    auto stage_w2 = [&](int q, int kb2, int p) {
        const __bf16* s0 = W2 + q * 128 + kb2 * 64;
        #pragma unroll
        for (int i = 0; i < 4; i++) {
            int idx = i * 512 + tid;
            int r = idx >> 3, kg = (idx & 7) ^ (r & 7);
            load_lds16(s0 + (size_t)r * 512 + kg * 8, &sB[p][idx * 8]);
        }
    };

    // gather h[src] -> sH (XOR-chunk layout) + first W1a slab; one drain.
    #pragma unroll
    for (int i = 0; i < 8; i++) {
        int idx = i * 512 + tid;
        int row = idx >> 5, kg = (idx & 31) ^ (row & 7);
        load_lds16(h + (size_t)s_src[row] * 256 + kg * 8, &sH[idx * 8]);
    }
    stage_w1(0, 0, 0);
    __syncthreads();

    f32_4 acc2[2][8];
    #pragma unroll
    for (int i = 0; i < 2; i++)
        #pragma unroll
        for (int j = 0; j < 8; j++) acc2[i][j] = zero4();

    #pragma unroll 1
    for (int q = 0; q < 4; q++) {
        // per-quarter bias+d registers (b1 pre-folded into dmat)
        const int colbase = q * 128 + wn * 64;
        float bd[2][4];
        #pragma unroll
        for (int nt = 0; nt < 4; nt++) {
            #pragma unroll
            for (int mt = 0; mt < 2; mt++) {
                int gid = blockIdx.x * 8 + wm * 2 + mt;
                bd[mt][nt] = (float)dmat[(size_t)gid * 512 + colbase + nt * 16 + ln];
            }
        }
        f32_4 acc1[2][4];
        #pragma unroll
        for (int i = 0; i < 2; i++)
            #pragma unroll
            for (int j = 0; j < 4; j++) acc1[i][j] = zero4();

        // ---- iter A: compute W1a(q,0) in sB[0]; stage W1a(q,1) -> sB[1] ----
        stage_w1(q, 1, 1);
        #pragma unroll
        for (int ks = 0; ks < 4; ks++) {
            int c = ks * 4 + quad;          // slab chunk 0..15 == sH chunk (kb=0)
            bf16_8 af[2], bfr[4];
            #pragma unroll
            for (int mt = 0; mt < 2; mt++) {
                int mr = wm * 32 + mt * 16 + ln;
                af[mt] = *(const bf16_8*)&sH[mr * 256 + ((c ^ (mr & 7)) * 8)];
            }
            #pragma unroll
            for (int nt = 0; nt < 4; nt++) {
                int nr = wn * 64 + nt * 16 + ln;
                bfr[nt] = *(const bf16_8*)&sB[0][nr * 128 + ((c ^ (nr & 7)) * 8)];
            }
            __builtin_amdgcn_s_setprio(1);
            #pragma unroll
            for (int mt = 0; mt < 2; mt++)
                #pragma unroll
                for (int nt = 0; nt < 4; nt++)
                    acc1[mt][nt] = __builtin_amdgcn_mfma_f32_16x16x32_bf16(af[mt], bfr[nt], acc1[mt][nt], 0, 0, 0);
            __builtin_amdgcn_s_setprio(0);
        }
        __syncthreads();

        // ---- iter B: compute W1a(q,1) in sB[1]; stage W2(q,0) -> sB[0] ----
        stage_w2(q, 0, 0);
        #pragma unroll
        for (int ks = 0; ks < 4; ks++) {
            int cb = ks * 4 + quad;         // slab chunk 0..15
            int ca = 16 + cb;               // sH chunk (kb=1 half)
            bf16_8 af[2], bfr[4];
            #pragma unroll
            for (int mt = 0; mt < 2; mt++) {
                int mr = wm * 32 + mt * 16 + ln;
                af[mt] = *(const bf16_8*)&sH[mr * 256 + ((ca ^ (mr & 7)) * 8)];
            }
            #pragma unroll
            for (int nt = 0; nt < 4; nt++) {
                int nr = wn * 64 + nt * 16 + ln;
                bfr[nt] = *(const bf16_8*)&sB[1][nr * 128 + ((cb ^ (nr & 7)) * 8)];
            }
            __builtin_amdgcn_s_setprio(1);
            #pragma unroll
            for (int mt = 0; mt < 2; mt++)
                #pragma unroll
                for (int nt = 0; nt < 4; nt++)
                    acc1[mt][nt] = __builtin_amdgcn_mfma_f32_16x16x32_bf16(af[mt], bfr[nt], acc1[mt][nt], 0, 0, 0);
            __builtin_amdgcn_s_setprio(0);
        }
        // epi1: gelu(acc1 + bd) -> sM1 (A-layout, add-rotation swizzle)
        #pragma unroll
        for (int mt = 0; mt < 2; mt++) {
            #pragma unroll
            for (int nt = 0; nt < 4; nt++) {
                #pragma unroll
                for (int r = 0; r < 4; r++) {
                    int row = wm * 32 + mt * 16 + quad * 4 + r;
                    int colq = wn * 64 + nt * 16 + ln;
                    float v = gelu_f(acc1[mt][nt][r] + bd[mt][nt]);
                    sM1[row * 128 + ((colq + row * 8) & 127)] = (__bf16)v;
                }
            }
        }
        __syncthreads();   // publish sM1; sB[1] reads done; W2(q,0) landed

        // ---- iter C: compute W2(q,0) in sB[0]; stage W2(q,1) -> sB[1] ----
        stage_w2(q, 1, 1);
        #pragma unroll
        for (int ks = 0; ks < 2; ks++) {
            int k0 = ks * 32 + quad * 8;
            int cb2 = ks * 4 + quad;        // slab chunk 0..7
            bf16_8 af[2], bfr[8];
            #pragma unroll
            for (int mt = 0; mt < 2; mt++) {
                int mr = wm * 32 + mt * 16 + ln;
                af[mt] = *(const bf16_8*)&sM1[mr * 128 + ((k0 + mr * 8) & 127)];
            }
            #pragma unroll
            for (int nt = 0; nt < 8; nt++) {
                int nr = wn * 128 + nt * 16 + ln;
                bfr[nt] = *(const bf16_8*)&sB[0][nr * 64 + ((cb2 ^ (nr & 7)) * 8)];
            }
            __builtin_amdgcn_s_setprio(1);
            #pragma unroll
            for (int mt = 0; mt < 2; mt++)
                #pragma unroll
                for (int nt = 0; nt < 8; nt++)
                    acc2[mt][nt] = __builtin_amdgcn_mfma_f32_16x16x32_bf16(af[mt], bfr[nt], acc2[mt][nt], 0, 0, 0);
            __builtin_amdgcn_s_setprio(0);
        }
        __syncthreads();

        // ---- iter D: compute W2(q,1) in sB[1]; stage W1a(q+1,0) -> sB[0] ----
        if (q < 3) stage_w1(q + 1, 0, 0);
        #pragma unroll
        for (int ks = 0; ks < 2; ks++) {
            int k0 = 64 + ks * 32 + quad * 8;
            int cb2 = ks * 4 + quad;
            bf16_8 af[2], bfr[8];
            #pragma unroll
            for (int mt = 0; mt < 2; mt++) {
                int mr = wm * 32 + mt * 16 + ln;
                af[mt] = *(const bf16_8*)&sM1[mr * 128 + ((k0 + mr * 8) & 127)];
            }
            #pragma unroll
            for (int nt = 0; nt < 8; nt++) {
                int nr = wn * 128 + nt * 16 + ln;
                bfr[nt] = *(const bf16_8*)&sB[1][nr * 64 + ((cb2 ^ (nr & 7)) * 8)];
            }
            __builtin_amdgcn_s_setprio(1);
            #pragma unroll
            for (int mt = 0; mt < 2; mt++)
                #pragma unroll
                for (int nt = 0; nt < 8; nt++)
                    acc2[mt][nt] = __builtin_amdgcn_mfma_f32_16x16x32_bf16(af[mt], bfr[nt], acc2[mt][nt], 0, 0, 0);
            __builtin_amdgcn_s_setprio(0);
        }
        __syncthreads();
    }

    // pool epilogue: mean of gelu(acc2 + b2) over each 16-row group
    #pragma unroll
    for (int nt = 0; nt < 8; nt++) {
        int col = wn * 128 + nt * 16 + ln;
        float bb = b2[col];
        #pragma unroll
        for (int mt = 0; mt < 2; mt++) {
            float s = gelu_f(acc2[mt][nt][0] + bb) + gelu_f(acc2[mt][nt][1] + bb)
                    + gelu_f(acc2[mt][nt][2] + bb) + gelu_f(acc2[mt][nt][3] + bb);
            s += __shfl_xor(s, 16);
            s += __shfl_xor(s, 32);
            if (quad == 0) {
                int dstn = edges[2 * (e0 + (wm * 2 + mt) * 16)];
                p2[(size_t)dstn * HID + col] = (__bf16)(s * 0.0625f);
            }
        }
    }
}

// ---------------- mgemm (thin 128x128): used for g1d / g3 ----------------
template<int K, int GMODE, int WLD, int WOFF, bool BIAS, bool POOL_, bool F32OUT>
__global__ __launch_bounds__(256, 3) void mgemm(
    const __bf16* __restrict__ Ag, const __bf16* __restrict__ h,
    const int* __restrict__ edges, const __bf16* __restrict__ W,
    const float* __restrict__ bias, __bf16* __restrict__ Cb,
    float* __restrict__ Cf, int NB, int Nfull, int e0)
{
    __shared__ __align__(16) __bf16 sA[128 * 64];
    __shared__ __align__(16) __bf16 sB[128 * 64];
    __shared__ int s_idx[128];

    const int tid  = threadIdx.x;
    const int mblk = blockIdx.x / NB;
    const int nblk = blockIdx.x % NB;
    const int m0 = mblk * 128, n0 = nblk * 128;
    const int wave = tid >> 6, lane = tid & 63, ln = lane & 15, quad = lane >> 4;
    const int wm = wave >> 1, wn = wave & 1;

    if (GMODE) {
        if (tid < 128) {
            int r = m0 + tid;
            s_idx[tid] = (GMODE == 1) ? edges[2 * (e0 + r) + 1]
                                      : edges[2 * (DEG * r)];
        }
        __syncthreads();
    }

    const __bf16* pA[4];
    const __bf16* pB[4];
    #pragma unroll
    for (int i = 0; i < 4; i++) {
        int idx = i * 256 + tid;
        int row = idx >> 3, kg = (idx & 7) ^ (row & 7);
        pA[i] = GMODE ? h + (size_t)s_idx[row] * HID + kg * 8
                      : Ag + (size_t)(m0 + row) * K + kg * 8;
        pB[i] = W + (size_t)(n0 + row) * WLD + WOFF + kg * 8;
    }
    const int ach = quad ^ (ln & 7);
    const int aof[2] = { (wm * 64 + ln) * 64 + ach * 8, (wm * 64 + ln) * 64 + (ach ^ 4) * 8 };
    const int bof[2] = { (wn * 64 + ln) * 64 + ach * 8, (wn * 64 + ln) * 64 + (ach ^ 4) * 8 };

    f32_4 acc[4][4];
    #pragma unroll
    for (int i = 0; i < 4; i++)
        #pragma unroll
        for (int j = 0; j < 4; j++) acc[i][j] = zero4();

    bf16_8 ar[4], br[4];
    #pragma unroll
    for (int i = 0; i < 4; i++) {
        ar[i] = *(const bf16_8*)pA[i];
        br[i] = *(const bf16_8*)pB[i];
    }

    #pragma unroll
    for (int kb = 0; kb < K / 64; kb++) {
        if (kb > 0) __syncthreads();
        #pragma unroll
        for (int i = 0; i < 4; i++) {
            int idx = i * 256 + tid;
            *(bf16_8*)&sA[idx * 8] = ar[i];
            *(bf16_8*)&sB[idx * 8] = br[i];
        }
        __syncthreads();
        if (kb + 1 < K / 64) {
            #pragma unroll
            for (int i = 0; i < 4; i++) {
                ar[i] = *(const bf16_8*)(pA[i] + (kb + 1) * 64);
                br[i] = *(const bf16_8*)(pB[i] + (kb + 1) * 64);
            }
        }
        #pragma unroll
        for (int ks = 0; ks < 2; ks++) {
            bf16_8 af[4], bfr[4];
            #pragma unroll
            for (int mt = 0; mt < 4; mt++) af[mt]  = *(const bf16_8*)&sA[aof[ks] + mt * 1024];
            #pragma unroll
            for (int nt = 0; nt < 4; nt++) bfr[nt] = *(const bf16_8*)&sB[bof[ks] + nt * 1024];
            #pragma unroll
            for (int mt = 0; mt < 4; mt++)
                #pragma unroll
                for (int nt = 0; nt < 4; nt++)
                    acc[mt][nt] = __builtin_amdgcn_mfma_f32_16x16x32_bf16(af[mt], bfr[nt], acc[mt][nt], 0, 0, 0);
        }
    }

    if (POOL_) {
        #pragma unroll
        for (int nt = 0; nt < 4; nt++) {
            int col = n0 + wn * 64 + nt * 16 + ln;
            float bb = BIAS ? bias[col] : 0.f;
            #pragma unroll
            for (int mt = 0; mt < 4; mt++) {
                float s = gelu_f(acc[mt][nt][0] + bb) + gelu_f(acc[mt][nt][1] + bb)
                        + gelu_f(acc[mt][nt][2] + bb) + gelu_f(acc[mt][nt][3] + bb);
                s += __shfl_xor(s, 16);
                s += __shfl_xor(s, 32);
                if (quad == 0) {
                    int eg  = e0 + m0 + wm * 64 + mt * 16;
                    int dstn = edges[2 * eg];
                    Cb[(size_t)dstn * HID + col] = (__bf16)(s * 0.0625f);
                }
            }
        }
    } else if (F32OUT) {
        #pragma unroll
        for (int nt = 0; nt < 4; nt++) {
            int col = n0 + wn * 64 + nt * 16 + ln;
            float bb = BIAS ? bias[col] : 0.f;
            #pragma unroll
            for (int mt = 0; mt < 4; mt++) {
                #pragma unroll
                for (int r = 0; r < 4; r++) {
                    int rowE = m0 + wm * 64 + mt * 16 + quad * 4 + r;
                    Cf[(size_t)rowE * Nfull + col] = acc[mt][nt][r] + bb;
                }
            }
        }
    } else {
        // raw bf16 transpose-store (+optional bias fold, used to bake b1 into d)
        __syncthreads();
        __bf16* sw = ((wave & 2) ? sB : sA) + (wave & 1) * 4096;
        #pragma unroll
        for (int nt = 0; nt < 4; nt++) {
            float bb = BIAS ? bias[n0 + wn * 64 + nt * 16 + ln] : 0.f;
            #pragma unroll
            for (int mt = 0; mt < 4; mt++) {
                #pragma unroll
                for (int r = 0; r < 4; r++) {
                    int rowL = mt * 16 + quad * 4 + r;
                    int colL = nt * 16 + ln;
                    sw[rowL * 64 + ((colL + rowL * 8) & 63)] = (__bf16)(acc[mt][nt][r] + bb);
                }
            }
        }
        __syncthreads();
        #pragma unroll
        for (int p = 0; p < 8; p++) {
            int rowL = p * 8 + (lane >> 3);
            int c8 = lane & 7;
            bf16_8 vv = *(const bf16_8*)&sw[rowL * 64 + ((c8 * 8 + rowL * 8) & 63)];
            int rowE = m0 + wm * 64 + rowL;
            *(bf16_8*)&Cb[(size_t)rowE * Nfull + n0 + wn * 64 + c8 * 8] = vv;
        }
    }
}

extern "C" void kernel_launch(void* const* d_in, const int* in_sizes, int n_in,
                              void* d_out, int out_size, void* d_ws, size_t ws_size,
                              hipStream_t stream) {
    const float* x     = (const float*)d_in[0];
    const float* pos   = (const float*)d_in[1];
    const int*   edges = (const int*)d_in[2];
    const float* ip_w1 = (const float*)d_in[4];
    const float* ip_b1 = (const float*)d_in[5];
    const float* ip_w2 = (const float*)d_in[6];
    const float* ip_b2 = (const float*)d_in[7];
    const float* ip_w3 = (const float*)d_in[8];
    const float* ip_b3 = (const float*)d_in[9];
    const float* bfour = (const float*)d_in[10];
    const float* mw1   = (const float*)d_in[11];
    const float* mb1   = (const float*)d_in[12];
    const float* mw2   = (const float*)d_in[13];
    const float* mb2   = (const float*)d_in[14];
    const float* mw3   = (const float*)d_in[15];
    const float* mb3   = (const float*)d_in[16];

    // workspace: hA 64 MB | weights 1.125 MB | dbuf 16 MB | p2 8 MB  (~89 MB)
    char* ws = (char*)d_ws;
    __bf16* hA = (__bf16*)ws;
    size_t off = (size_t)N_NODES * HID * 2;
    __bf16* wb = (__bf16*)(ws + off);
    off += (size_t)589824 * 2;
    off = (off + 255) & ~(size_t)255;
    __bf16* dbuf = (__bf16*)(ws + off);                      // d = h_dst@W1b^T + b1
    off += (size_t)N_DST * 512 * 2;
    __bf16* p2 = (__bf16*)(ws + off);                        // pooled m2
    off += (size_t)N_DST * HID * 2;

    __bf16* w2b  = wb;
    __bf16* w3b  = wb + 65536;
    __bf16* mw1b = wb + 131072;
    __bf16* mw2b = wb + 393216;
    __bf16* mw3b = wb + 524288;

    prep_kernel<<<2304, 256, 0, stream>>>(wb, ip_w2, ip_w3, mw1, mw2, mw3);

    // fused encoder L1+L2+L3 -> hA (no h1 round-trip)
    enc123_kernel<<<2048, 256, 0, stream>>>(x, ip_w1, ip_b1, hA,
                                            w2b, ip_b2, w3b, ip_b3, pos, bfour);

    // d[g] = h[dst(g)] @ W1b^T + b1  (16384 x 512, K=256)
    mgemm<256, 2, 512, 256, true, false, false><<<512, 256, 0, stream>>>(
        nullptr, hA, edges, mw1b, mb1, dbuf, nullptr, 4, 512, 0);

    // fused message MLP + pool: p2[dst] = mean(gelu(gelu(h_src@W1a^T+d)@W2^T+b2))
    msg_fused<<<2048, 512, 0, stream>>>(hA, edges, mw1b, dbuf, mw2b, mb2, p2);

    // out = p2 @ W3^T + b3  (16384 x 256, K=256), fp32
    mgemm<256, 0, 256, 0, true, false, true><<<256, 256, 0, stream>>>(
        p2, nullptr, nullptr, mw3b, mb3, nullptr, (float*)d_out, 2, 256, 0);
}

// Round 9
// 403.960 us; speedup vs baseline: 1.0574x; 1.0009x over previous
//
#include <hip/hip_runtime.h>
#include <math.h>

#define N_NODES 131072
#define N_DST   16384
#define DEG     16
#define HID     256
#define N_EDGES 262144

typedef __bf16 bf16_8 __attribute__((ext_vector_type(8)));
typedef float  f32_4  __attribute__((ext_vector_type(4)));

// tanh-approx gelu, |err| <~1e-3 (threshold 2.2e-2).
// log2(e) folded into polynomial constants (direct v_exp_f32); IEEE divide
// replaced by v_rcp_f32. ~7 VALU ops per gelu.
__device__ __forceinline__ float gelu_f(float v) {
    float u = fmaf(v * v, -0.10294324f, -2.30220819f) * v;
    float e;
    asm("v_exp_f32 %0, %1" : "=v"(e) : "v"(u));   // e = 2^u = exp(-t)
    return v * __builtin_amdgcn_rcpf(1.0f + e);
}
__device__ __forceinline__ f32_4 zero4() {
    f32_4 z; z[0] = 0.f; z[1] = 0.f; z[2] = 0.f; z[3] = 0.f; return z;
}

// async global->LDS, 16B per lane. LDS side must be wave-uniform base + lane*16.
__device__ __forceinline__ void load_lds16(const __bf16* g, __bf16* l) {
    __builtin_amdgcn_global_load_lds(
        (__attribute__((address_space(1))) void*)g,
        (__attribute__((address_space(3))) void*)l, 16, 0, 0);
}

// ---------------- prep: fp32 -> bf16 weights ----------------
__global__ void prep_kernel(__bf16* __restrict__ out,
                            const float* __restrict__ w2,
                            const float* __restrict__ w3,
                            const float* __restrict__ mw1,
                            const float* __restrict__ mw2,
                            const float* __restrict__ mw3) {
    int i = blockIdx.x * 256 + threadIdx.x;
    if (i >= 589824) return;
    float v;
    if      (i <  65536) v = w2[i];
    else if (i < 131072) v = w3[i - 65536];
    else if (i < 393216) v = mw1[i - 131072];
    else if (i < 524288) v = mw2[i - 393216];
    else                 v = mw3[i - 524288];
    out[i] = (__bf16)v;
}

// ---------------- enc123: fused encoder L1+L2+L3 -> hA ----------------------
// 64 rows/block, 256 thr. enc1 inlined in the prologue (bit-identical math),
// written straight to sH in XOR-chunk layout. NEW (R9): weight staging uses
// 16 KB HALF-slabs ping-ponged in sBh[2] (same 32 KB footprint) -- stage(hs+1)
// issues before compute(hs), so the vmcnt(0) drain inside each sync is hidden
// under the MFMA nest (was fully exposed: compute/sync/stage/sync). hs order
// == (kb,ks) order -> bit-identical numerics. Half-slab swizzle: slot =
// chunk ^ ((row>>1)&3), start-bank spread over 8 groups -> 2-way alias (free).
// LDS = 32 (sH) + 32 (sBh) = 64 KB -> 2 blocks/CU.
__global__ __launch_bounds__(256, 2) void enc123_kernel(
    const float* __restrict__ x, const float* __restrict__ ew1,
    const float* __restrict__ eb1, __bf16* __restrict__ hA,
    const __bf16* __restrict__ W2, const float* __restrict__ b2,
    const __bf16* __restrict__ W3, const float* __restrict__ b3,
    const float* __restrict__ pos, const float* __restrict__ bfour)
{
    __shared__ __align__(16) __bf16 sH[64 * 256];   // 32 KB h1 -> h2
    __shared__ __align__(16) __bf16 sBh[2][8192];   // 2x16 KB W half-slabs

    const int tid = threadIdx.x;
    const int m0  = blockIdx.x * 64;
    const int wave = tid >> 6, lane = tid & 63, ln = lane & 15, quad = lane >> 4;
    const int wm = wave >> 1, wn = wave & 1;

    // half-slab hs covers cols [hs*32, hs*32+32) of a [256][256] W matrix.
    auto stage_half = [&](const __bf16* W, int hs, int p) {
        #pragma unroll
        for (int i = 0; i < 4; i++) {
            int idx = i * 256 + tid;            // 0..1023
            int r = idx >> 2, sl = idx & 3;
            int kg = sl ^ ((r >> 1) & 3);       // global chunk at this slot
            load_lds16(W + (size_t)r * 256 + hs * 32 + kg * 8, &sBh[p][idx * 8]);
        }
    };

    // prologue: issue W2 half 0 DMA, then compute h1 under it (exact enc1 math).
    stage_half(W2, 0, 0);
    {
        const int c8 = tid & 31;     // col-chunk 0..31 (8 cols)
        const int rl = tid >> 5;     // row phase 0..7
        float w[24], bb[8];
        #pragma unroll
        for (int i = 0; i < 6; i++) *(float4*)&w[i * 4] = ((const float4*)ew1)[c8 * 6 + i];
        *(float4*)&bb[0] = ((const float4*)eb1)[c8 * 2 + 0];
        *(float4*)&bb[4] = ((const float4*)eb1)[c8 * 2 + 1];
        #pragma unroll
        for (int rr = 0; rr < 8; rr++) {
            int row = rr * 8 + rl;
            int g = m0 + row;
            float x0 = x[g * 3 + 0], x1 = x[g * 3 + 1], x2 = x[g * 3 + 2];
            bf16_8 o;
            #pragma unroll
            for (int j = 0; j < 8; j++) {
                float v = fmaf(x2, w[j * 3 + 2],
                          fmaf(x1, w[j * 3 + 1],
                          fmaf(x0, w[j * 3 + 0], bb[j])));
                o[j] = (__bf16)gelu_f(v);
            }
            *(bf16_8*)&sH[row * 256 + ((c8 ^ (row & 7)) * 8)] = o;
        }
    }
    __syncthreads();   // sH h1 visible + W2 half 0 landed

    f32_4 acc[2][8];
    #pragma unroll
    for (int i = 0; i < 2; i++)
        #pragma unroll
        for (int j = 0; j < 8; j++) acc[i][j] = zero4();

    // ---- phase 1: h2 = gelu(h1 @ W2^T + b2) ----  (hs = kb*2+ks, K=32 each)
    #pragma unroll
    for (int hs = 0; hs < 8; hs++) {
        if (hs < 7) stage_half(W2, hs + 1, (hs + 1) & 1);
        else        stage_half(W3, 0, 0);            // buf0 free (last read hs=6)
        {
            int c = (hs & 1) * 4 + quad;             // chunk within 64-col slab
            bf16_8 af[2], bfr[8];
            #pragma unroll
            for (int mt = 0; mt < 2; mt++) {
                int mr = wm * 32 + mt * 16 + ln;
                af[mt] = *(const bf16_8*)&sH[mr * 256 + (((hs >> 1) * 8 + (c ^ (mr & 7))) * 8)];
            }
            #pragma unroll
            for (int nt = 0; nt < 8; nt++) {
                int nr = wn * 128 + nt * 16 + ln;
                int sl = quad ^ ((nr >> 1) & 3);
                bfr[nt] = *(const bf16_8*)&sBh[hs & 1][nr * 32 + sl * 8];
            }
            __builtin_amdgcn_s_setprio(1);
            #pragma unroll
            for (int mt = 0; mt < 2; mt++)
                #pragma unroll
                for (int nt = 0; nt < 8; nt++)
                    acc[mt][nt] = __builtin_amdgcn_mfma_f32_16x16x32_bf16(af[mt], bfr[nt], acc[mt][nt], 0, 0, 0);
            __builtin_amdgcn_s_setprio(0);
        }
        __syncthreads();
    }
    // epi1 -> sH (add-rotation swizzle); own-row band only
    #pragma unroll
    for (int nt = 0; nt < 8; nt++) {
        int col = wn * 128 + nt * 16 + ln;
        float bb = b2[col];
        #pragma unroll
        for (int mt = 0; mt < 2; mt++) {
            #pragma unroll
            for (int r = 0; r < 4; r++) {
                int row = wm * 32 + mt * 16 + quad * 4 + r;
                sH[row * 256 + ((col + row * 8) & 255)] = (__bf16)gelu_f(acc[mt][nt][r] + bb);
            }
        }
    }
    #pragma unroll
    for (int i = 0; i < 2; i++)
        #pragma unroll
        for (int j = 0; j < 8; j++) acc[i][j] = zero4();
    __syncthreads();   // h2 visible (W3 half 0 landed at hs=7's sync)

    // ---- phase 2: h = h2 @ W3^T + b3 + fourier ----
    #pragma unroll
    for (int hs = 0; hs < 8; hs++) {
        if (hs < 7) stage_half(W3, hs + 1, (hs + 1) & 1);
        {
            int k0 = hs * 32 + quad * 8;
            bf16_8 af[2], bfr[8];
            #pragma unroll
            for (int mt = 0; mt < 2; mt++) {
                int mr = wm * 32 + mt * 16 + ln;
                af[mt] = *(const bf16_8*)&sH[mr * 256 + ((k0 + mr * 8) & 255)];
            }
            #pragma unroll
            for (int nt = 0; nt < 8; nt++) {
                int nr = wn * 128 + nt * 16 + ln;
                int sl = quad ^ ((nr >> 1) & 3);
                bfr[nt] = *(const bf16_8*)&sBh[hs & 1][nr * 32 + sl * 8];
            }
            __builtin_amdgcn_s_setprio(1);
            #pragma unroll
            for (int mt = 0; mt < 2; mt++)
                #pragma unroll
                for (int nt = 0; nt < 8; nt++)
                    acc[mt][nt] = __builtin_amdgcn_mfma_f32_16x16x32_bf16(af[mt], bfr[nt], acc[mt][nt], 0, 0, 0);
            __builtin_amdgcn_s_setprio(0);
        }
        __syncthreads();
    }
    // epi2: + b3 + fourier -> per-wave transpose (reuse sBh) -> 16B stores
    __bf16* buf = &sBh[0][0] + wave * 4096;
    float b3r[8], Bc0[8], Bc1[8];
    #pragma unroll
    for (int nt = 0; nt < 8; nt++) {
        int col = wn * 128 + nt * 16 + ln;
        b3r[nt] = b3[col];
        int jm = col & 127;
        Bc0[nt] = bfour[jm * 2 + 0];
        Bc1[nt] = bfour[jm * 2 + 1];
    }
    const bool iscos = (wn == 0);
    #pragma unroll
    for (int mt = 0; mt < 2; mt++) {
        #pragma unroll
        for (int r = 0; r < 4; r++) {
            int rowL = mt * 16 + quad * 4 + r;
            int rowE = m0 + wm * 32 + rowL;
            float p0 = pos[rowE * 2 + 0], p1 = pos[rowE * 2 + 1];
            #pragma unroll
            for (int nt = 0; nt < 8; nt++) {
                float f = 6.2831853071795864f * fmaf(p1, Bc1[nt], p0 * Bc0[nt]);
                float v = acc[mt][nt][r] + b3r[nt] + (iscos ? __cosf(f) : __sinf(f));
                int colL = nt * 16 + ln;
                buf[rowL * 128 + ((colL + rowL * 8) & 127)] = (__bf16)v;
            }
        }
    }
    // wave-private buf: same-wave RAW ordered by lgkmcnt (proven pattern)
    #pragma unroll
    for (int p = 0; p < 8; p++) {
        int rowL = p * 4 + (lane >> 4);
        int c8 = lane & 15;
        bf16_8 vv = *(const bf16_8*)&buf[rowL * 128 + ((c8 * 8 + rowL * 8) & 127)];
        *(bf16_8*)&hA[(size_t)(m0 + wm * 32 + rowL) * 256 + wn * 128 + c8 * 8] = vv;
    }
}

// ---------------- msg_fused (R8 verbatim -- frozen anchor, 242 us) ---------
__global__ __launch_bounds__(512, 1) void msg_fused(
    const __bf16* __restrict__ h, const int* __restrict__ edges,
    const __bf16* __restrict__ W1a, const __bf16* __restrict__ dmat,
    const __bf16* __restrict__ W2, const float* __restrict__ b2,
    __bf16* __restrict__ p2)
{
    __shared__ __align__(16) __bf16 sH[32768];       // 64 KB gathered h_src [128][256]
    __shared__ __align__(16) __bf16 sB[2][16384];    // 64 KB double-buffered W slab
    __shared__ __align__(16) __bf16 sM1[16384];      // 32 KB m1 quarter (A-layout)

    const int tid = threadIdx.x;
    const int e0  = blockIdx.x * 128;
    const int wave = tid >> 6, lane = tid & 63, ln = lane & 15, quad = lane >> 4;
    const int wm = wave >> 1, wn = wave & 1;   // 4 x 2 wave grid

    int* s_src = (int*)sM1;   // overlay: consumed in gather prologue only
    if (tid < 128) s_src[tid] = edges[2 * (e0 + tid) + 1];
    __syncthreads();

    auto stage_w1 = [&](int q, int kb, int p) {
        const __bf16* s0 = W1a + (size_t)(q * 128) * 512 + kb * 128;
        #pragma unroll
        for (int i = 0; i < 4; i++) {
            int idx = i * 512 + tid;
            int r = idx >> 4, kg = (idx & 15) ^ (r & 7);
            load_lds16(s0 + r * 512 + kg * 8, &sB[p][idx * 8]);
        }
    };
    auto stage_w2 = [&](int q, int kb2, int p) {
        const __bf16* s0 = W2 + q * 128 + kb2 * 64;
        #pragma unroll
        for (int i = 0; i < 4; i++) {
            int idx = i * 512 + tid;
            int r = idx >> 3, kg = (idx & 7) ^ (r & 7);
            load_lds16(s0 + (size_t)r * 512 + kg * 8, &sB[p][idx * 8]);
        }
    };

    // gather h[src] -> sH (XOR-chunk layout) + first W1a slab; one drain.
    #pragma unroll
    for (int i = 0; i < 8; i++) {
        int idx = i * 512 + tid;
        int row = idx >> 5, kg = (idx & 31) ^ (row & 7);
        load_lds16(h + (size_t)s_src[row] * 256 + kg * 8, &sH[idx * 8]);
    }
    stage_w1(0, 0, 0);
    __syncthreads();

    f32_4 acc2[2][8];
    #pragma unroll
    for (int i = 0; i < 2; i++)
        #pragma unroll
        for (int j = 0; j < 8; j++) acc2[i][j] = zero4();

    #pragma unroll 1
    for (int q = 0; q < 4; q++) {
        // per-quarter bias+d registers (b1 pre-folded into dmat)
        const int colbase = q * 128 + wn * 64;
        float bd[2][4];
        #pragma unroll
        for (int nt = 0; nt < 4; nt++) {
            #pragma unroll
            for (int mt = 0; mt < 2; mt++) {
                int gid = blockIdx.x * 8 + wm * 2 + mt;
                bd[mt][nt] = (float)dmat[(size_t)gid * 512 + colbase + nt * 16 + ln];
            }
        }
        f32_4 acc1[2][4];
        #pragma unroll
        for (int i = 0; i < 2; i++)
            #pragma unroll
            for (int j = 0; j < 4; j++) acc1[i][j] = zero4();

        // ---- iter A: compute W1a(q,0) in sB[0]; stage W1a(q,1) -> sB[1] ----
        stage_w1(q, 1, 1);
        #pragma unroll
        for (int ks = 0; ks < 4; ks++) {
            int c = ks * 4 + quad;          // slab chunk 0..15 == sH chunk (kb=0)
            bf16_8 af[2], bfr[4];
            #pragma unroll
            for (int mt = 0; mt < 2; mt++) {
                int mr = wm * 32 + mt * 16 + ln;
                af[mt] = *(const bf16_8*)&sH[mr * 256 + ((c ^ (mr & 7)) * 8)];
            }
            #pragma unroll
            for (int nt = 0; nt < 4; nt++) {
                int nr = wn * 64 + nt * 16 + ln;
                bfr[nt] = *(const bf16_8*)&sB[0][nr * 128 + ((c ^ (nr & 7)) * 8)];
            }
            __builtin_amdgcn_s_setprio(1);
            #pragma unroll
            for (int mt = 0; mt < 2; mt++)
                #pragma unroll
                for (int nt = 0; nt < 4; nt++)
                    acc1[mt][nt] = __builtin_amdgcn_mfma_f32_16x16x32_bf16(af[mt], bfr[nt], acc1[mt][nt], 0, 0, 0);
            __builtin_amdgcn_s_setprio(0);
        }
        __syncthreads();

        // ---- iter B: compute W1a(q,1) in sB[1]; stage W2(q,0) -> sB[0] ----
        stage_w2(q, 0, 0);
        #pragma unroll
        for (int ks = 0; ks < 4; ks++) {
            int cb = ks * 4 + quad;         // slab chunk 0..15
            int ca = 16 + cb;               // sH chunk (kb=1 half)
            bf16_8 af[2], bfr[4];
            #pragma unroll
            for (int mt = 0; mt < 2; mt++) {
                int mr = wm * 32 + mt * 16 + ln;
                af[mt] = *(const bf16_8*)&sH[mr * 256 + ((ca ^ (mr & 7)) * 8)];
            }
            #pragma unroll
            for (int nt = 0; nt < 4; nt++) {
                int nr = wn * 64 + nt * 16 + ln;
                bfr[nt] = *(const bf16_8*)&sB[1][nr * 128 + ((cb ^ (nr & 7)) * 8)];
            }
            __builtin_amdgcn_s_setprio(1);
            #pragma unroll
            for (int mt = 0; mt < 2; mt++)
                #pragma unroll
                for (int nt = 0; nt < 4; nt++)
                    acc1[mt][nt] = __builtin_amdgcn_mfma_f32_16x16x32_bf16(af[mt], bfr[nt], acc1[mt][nt], 0, 0, 0);
            __builtin_amdgcn_s_setprio(0);
        }
        // epi1: gelu(acc1 + bd) -> sM1 (A-layout, add-rotation swizzle)
        #pragma unroll
        for (int mt = 0; mt < 2; mt++) {
            #pragma unroll
            for (int nt = 0; nt < 4; nt++) {
                #pragma unroll
                for (int r = 0; r < 4; r++) {
                    int row = wm * 32 + mt * 16 + quad * 4 + r;
                    int colq = wn * 64 + nt * 16 + ln;
                    float v = gelu_f(acc1[mt][nt][r] + bd[mt][nt]);
                    sM1[row * 128 + ((colq + row * 8) & 127)] = (__bf16)v;
                }
            }
        }
        __syncthreads();   // publish sM1; sB[1] reads done; W2(q,0) landed

        // ---- iter C: compute W2(q,0) in sB[0]; stage W2(q,1) -> sB[1] ----
        stage_w2(q, 1, 1);
        #pragma unroll
        for (int ks = 0; ks < 2; ks++) {
            int k0 = ks * 32 + quad * 8;
            int cb2 = ks * 4 + quad;        // slab chunk 0..7
            bf16_8 af[2], bfr[8];
            #pragma unroll
            for (int mt = 0; mt < 2; mt++) {
                int mr = wm * 32 + mt * 16 + ln;
                af[mt] = *(const bf16_8*)&sM1[mr * 128 + ((k0 + mr * 8) & 127)];
            }
            #pragma unroll
            for (int nt = 0; nt < 8; nt++) {
                int nr = wn * 128 + nt * 16 + ln;
                bfr[nt] = *(const bf16_8*)&sB[0][nr * 64 + ((cb2 ^ (nr & 7)) * 8)];
            }
            __builtin_amdgcn_s_setprio(1);
            #pragma unroll
            for (int mt = 0; mt < 2; mt++)
                #pragma unroll
                for (int nt = 0; nt < 8; nt++)
                    acc2[mt][nt] = __builtin_amdgcn_mfma_f32_16x16x32_bf16(af[mt], bfr[nt], acc2[mt][nt], 0, 0, 0);
            __builtin_amdgcn_s_setprio(0);
        }
        __syncthreads();

        // ---- iter D: compute W2(q,1) in sB[1]; stage W1a(q+1,0) -> sB[0] ----
        if (q < 3) stage_w1(q + 1, 0, 0);
        #pragma unroll
        for (int ks = 0; ks < 2; ks++) {
            int k0 = 64 + ks * 32 + quad * 8;
            int cb2 = ks * 4 + quad;
            bf16_8 af[2], bfr[8];
            #pragma unroll
            for (int mt = 0; mt < 2; mt++) {
                int mr = wm * 32 + mt * 16 + ln;
                af[mt] = *(const bf16_8*)&sM1[mr * 128 + ((k0 + mr * 8) & 127)];
            }
            #pragma unroll
            for (int nt = 0; nt < 8; nt++) {
                int nr = wn * 128 + nt * 16 + ln;
                bfr[nt] = *(const bf16_8*)&sB[1][nr * 64 + ((cb2 ^ (nr & 7)) * 8)];
            }
            __builtin_amdgcn_s_setprio(1);
            #pragma unroll
            for (int mt = 0; mt < 2; mt++)
                #pragma unroll
                for (int nt = 0; nt < 8; nt++)
                    acc2[mt][nt] = __builtin_amdgcn_mfma_f32_16x16x32_bf16(af[mt], bfr[nt], acc2[mt][nt], 0, 0, 0);
            __builtin_amdgcn_s_setprio(0);
        }
        __syncthreads();
    }

    // pool epilogue: mean of gelu(acc2 + b2) over each 16-row group
    #pragma unroll
    for (int nt = 0; nt < 8; nt++) {
        int col = wn * 128 + nt * 16 + ln;
        float bb = b2[col];
        #pragma unroll
        for (int mt = 0; mt < 2; mt++) {
            float s = gelu_f(acc2[mt][nt][0] + bb) + gelu_f(acc2[mt][nt][1] + bb)
                    + gelu_f(acc2[mt][nt][2] + bb) + gelu_f(acc2[mt][nt][3] + bb);
            s += __shfl_xor(s, 16);
            s += __shfl_xor(s, 32);
            if (quad == 0) {
                int dstn = edges[2 * (e0 + (wm * 2 + mt) * 16)];
                p2[(size_t)dstn * HID + col] = (__bf16)(s * 0.0625f);
            }
        }
    }
}

// ---------------- mgemm (thin 128x128): used for g1d / g3 ----------------
template<int K, int GMODE, int WLD, int WOFF, bool BIAS, bool POOL_, bool F32OUT>
__global__ __launch_bounds__(256, 3) void mgemm(
    const __bf16* __restrict__ Ag, const __bf16* __restrict__ h,
    const int* __restrict__ edges, const __bf16* __restrict__ W,
    const float* __restrict__ bias, __bf16* __restrict__ Cb,
    float* __restrict__ Cf, int NB, int Nfull, int e0)
{
    __shared__ __align__(16) __bf16 sA[128 * 64];
    __shared__ __align__(16) __bf16 sB[128 * 64];
    __shared__ int s_idx[128];

    const int tid  = threadIdx.x;
    const int mblk = blockIdx.x / NB;
    const int nblk = blockIdx.x % NB;
    const int m0 = mblk * 128, n0 = nblk * 128;
    const int wave = tid >> 6, lane = tid & 63, ln = lane & 15, quad = lane >> 4;
    const int wm = wave >> 1, wn = wave & 1;

    if (GMODE) {
        if (tid < 128) {
            int r = m0 + tid;
            s_idx[tid] = (GMODE == 1) ? edges[2 * (e0 + r) + 1]
                                      : edges[2 * (DEG * r)];
        }
        __syncthreads();
    }

    const __bf16* pA[4];
    const __bf16* pB[4];
    #pragma unroll
    for (int i = 0; i < 4; i++) {
        int idx = i * 256 + tid;
        int row = idx >> 3, kg = (idx & 7) ^ (row & 7);
        pA[i] = GMODE ? h + (size_t)s_idx[row] * HID + kg * 8
                      : Ag + (size_t)(m0 + row) * K + kg * 8;
        pB[i] = W + (size_t)(n0 + row) * WLD + WOFF + kg * 8;
    }
    const int ach = quad ^ (ln & 7);
    const int aof[2] = { (wm * 64 + ln) * 64 + ach * 8, (wm * 64 + ln) * 64 + (ach ^ 4) * 8 };
    const int bof[2] = { (wn * 64 + ln) * 64 + ach * 8, (wn * 64 + ln) * 64 + (ach ^ 4) * 8 };

    f32_4 acc[4][4];
    #pragma unroll
    for (int i = 0; i < 4; i++)
        #pragma unroll
        for (int j = 0; j < 4; j++) acc[i][j] = zero4();

    bf16_8 ar[4], br[4];
    #pragma unroll
    for (int i = 0; i < 4; i++) {
        ar[i] = *(const bf16_8*)pA[i];
        br[i] = *(const bf16_8*)pB[i];
    }

    #pragma unroll
    for (int kb = 0; kb < K / 64; kb++) {
        if (kb > 0) __syncthreads();
        #pragma unroll
        for (int i = 0; i < 4; i++) {
            int idx = i * 256 + tid;
            *(bf16_8*)&sA[idx * 8] = ar[i];
            *(bf16_8*)&sB[idx * 8] = br[i];
        }
        __syncthreads();
        if (kb + 1 < K / 64) {
            #pragma unroll
            for (int i = 0; i < 4; i++) {
                ar[i] = *(const bf16_8*)(pA[i] + (kb + 1) * 64);
                br[i] = *(const bf16_8*)(pB[i] + (kb + 1) * 64);
            }
        }
        #pragma unroll
        for (int ks = 0; ks < 2; ks++) {
            bf16_8 af[4], bfr[4];
            #pragma unroll
            for (int mt = 0; mt < 4; mt++) af[mt]  = *(const bf16_8*)&sA[aof[ks] + mt * 1024];
            #pragma unroll
            for (int nt = 0; nt < 4; nt++) bfr[nt] = *(const bf16_8*)&sB[bof[ks] + nt * 1024];
            __builtin_amdgcn_s_setprio(1);
            #pragma unroll
            for (int mt = 0; mt < 4; mt++)
                #pragma unroll
                for (int nt = 0; nt < 4; nt++)
                    acc[mt][nt] = __builtin_amdgcn_mfma_f32_16x16x32_bf16(af[mt], bfr[nt], acc[mt][nt], 0, 0, 0);
            __builtin_amdgcn_s_setprio(0);
        }
    }

    if (POOL_) {
        #pragma unroll
        for (int nt = 0; nt < 4; nt++) {
            int col = n0 + wn * 64 + nt * 16 + ln;
            float bb = BIAS ? bias[col] : 0.f;
            #pragma unroll
            for (int mt = 0; mt < 4; mt++) {
                float s = gelu_f(acc[mt][nt][0] + bb) + gelu_f(acc[mt][nt][1] + bb)
                        + gelu_f(acc[mt][nt][2] + bb) + gelu_f(acc[mt][nt][3] + bb);
                s += __shfl_xor(s, 16);
                s += __shfl_xor(s, 32);
                if (quad == 0) {
                    int eg  = e0 + m0 + wm * 64 + mt * 16;
                    int dstn = edges[2 * eg];
                    Cb[(size_t)dstn * HID + col] = (__bf16)(s * 0.0625f);
                }
            }
        }
    } else if (F32OUT) {
        #pragma unroll
        for (int nt = 0; nt < 4; nt++) {
            int col = n0 + wn * 64 + nt * 16 + ln;
            float bb = BIAS ? bias[col] : 0.f;
            #pragma unroll
            for (int mt = 0; mt < 4; mt++) {
                #pragma unroll
                for (int r = 0; r < 4; r++) {
                    int rowE = m0 + wm * 64 + mt * 16 + quad * 4 + r;
                    Cf[(size_t)rowE * Nfull + col] = acc[mt][nt][r] + bb;
                }
            }
        }
    } else {
        // raw bf16 transpose-store (+optional bias fold, used to bake b1 into d)
        __syncthreads();
        __bf16* sw = ((wave & 2) ? sB : sA) + (wave & 1) * 4096;
        #pragma unroll
        for (int nt = 0; nt < 4; nt++) {
            float bb = BIAS ? bias[n0 + wn * 64 + nt * 16 + ln] : 0.f;
            #pragma unroll
            for (int mt = 0; mt < 4; mt++) {
                #pragma unroll
                for (int r = 0; r < 4; r++) {
                    int rowL = mt * 16 + quad * 4 + r;
                    int colL = nt * 16 + ln;
                    sw[rowL * 64 + ((colL + rowL * 8) & 63)] = (__bf16)(acc[mt][nt][r] + bb);
                }
            }
        }
        __syncthreads();
        #pragma unroll
        for (int p = 0; p < 8; p++) {
            int rowL = p * 8 + (lane >> 3);
            int c8 = lane & 7;
            bf16_8 vv = *(const bf16_8*)&sw[rowL * 64 + ((c8 * 8 + rowL * 8) & 63)];
            int rowE = m0 + wm * 64 + rowL;
            *(bf16_8*)&Cb[(size_t)rowE * Nfull + n0 + wn * 64 + c8 * 8] = vv;
        }
    }
}

extern "C" void kernel_launch(void* const* d_in, const int* in_sizes, int n_in,
                              void* d_out, int out_size, void* d_ws, size_t ws_size,
                              hipStream_t stream) {
    const float* x     = (const float*)d_in[0];
    const float* pos   = (const float*)d_in[1];
    const int*   edges = (const int*)d_in[2];
    const float* ip_w1 = (const float*)d_in[4];
    const float* ip_b1 = (const float*)d_in[5];
    const float* ip_w2 = (const float*)d_in[6];
    const float* ip_b2 = (const float*)d_in[7];
    const float* ip_w3 = (const float*)d_in[8];
    const float* ip_b3 = (const float*)d_in[9];
    const float* bfour = (const float*)d_in[10];
    const float* mw1   = (const float*)d_in[11];
    const float* mb1   = (const float*)d_in[12];
    const float* mw2   = (const float*)d_in[13];
    const float* mb2   = (const float*)d_in[14];
    const float* mw3   = (const float*)d_in[15];
    const float* mb3   = (const float*)d_in[16];

    // workspace: hA 64 MB | weights 1.125 MB | dbuf 16 MB | p2 8 MB  (~89 MB)
    char* ws = (char*)d_ws;
    __bf16* hA = (__bf16*)ws;
    size_t off = (size_t)N_NODES * HID * 2;
    __bf16* wb = (__bf16*)(ws + off);
    off += (size_t)589824 * 2;
    off = (off + 255) & ~(size_t)255;
    __bf16* dbuf = (__bf16*)(ws + off);                      // d = h_dst@W1b^T + b1
    off += (size_t)N_DST * 512 * 2;
    __bf16* p2 = (__bf16*)(ws + off);                        // pooled m2
    off += (size_t)N_DST * HID * 2;

    __bf16* w2b  = wb;
    __bf16* w3b  = wb + 65536;
    __bf16* mw1b = wb + 131072;
    __bf16* mw2b = wb + 393216;
    __bf16* mw3b = wb + 524288;

    prep_kernel<<<2304, 256, 0, stream>>>(wb, ip_w2, ip_w3, mw1, mw2, mw3);

    // fused encoder L1+L2+L3 -> hA (no h1 round-trip)
    enc123_kernel<<<2048, 256, 0, stream>>>(x, ip_w1, ip_b1, hA,
                                            w2b, ip_b2, w3b, ip_b3, pos, bfour);

    // d[g] = h[dst(g)] @ W1b^T + b1  (16384 x 512, K=256)
    mgemm<256, 2, 512, 256, true, false, false><<<512, 256, 0, stream>>>(
        nullptr, hA, edges, mw1b, mb1, dbuf, nullptr, 4, 512, 0);

    // fused message MLP + pool: p2[dst] = mean(gelu(gelu(h_src@W1a^T+d)@W2^T+b2))
    msg_fused<<<2048, 512, 0, stream>>>(hA, edges, mw1b, dbuf, mw2b, mb2, p2);

    // out = p2 @ W3^T + b3  (16384 x 256, K=256), fp32
    mgemm<256, 0, 256, 0, true, false, true><<<256, 256, 0, stream>>>(
        p2, nullptr, nullptr, mw3b, mb3, nullptr, (float*)d_out, 2, 256, 0);
}